// Round 8
// baseline (306.779 us; speedup 1.0000x reference)
//
#include <hip/hip_runtime.h>

#define NROWS 32
#define SPAN 960      // samples per A-thread (1000 * 960 = 960000)
#define ATHREADS 1000 // active threads per A-block
#define STRIP 64      // strip granularity handed to kernel B
#define NSTORE 15     // SPAN / STRIP

// XLA-CPU f32 mirror: division-by-constant is rewritten to multiplication
// by the f32 reciprocal (algebraic simplifier). No FMA contraction.
//   x  = fl(fl(t+0.5) * fl(1/480)) - 0.5; clip; i0=floor; w=x-i0 (exact)
//   up = fl(fl(a0*fl(1-w)) + fl(a1*w)),  a = relu(f0)
//   d  = fl(up * fl(1/48000))
__device__ __forceinline__ void sample_udA(const float* __restrict__ frow,
                                           int L, int t, float& up, float& d) {
  const float R480 = 1.0f / 480.0f;      // constant-folded to RN(1/480)
  const float R48000 = 1.0f / 48000.0f;  // RN(1/48000)
  float x = __fsub_rn(__fmul_rn(__fadd_rn((float)t, 0.5f), R480), 0.5f);
  x = fminf(fmaxf(x, 0.0f), (float)(L - 1));
  const int i0 = (int)x;                    // x >= 0: trunc == floor
  const float w = __fsub_rn(x, (float)i0);  // exact
  const int i1 = min(i0 + 1, L - 1);
  const float a0 = fmaxf(frow[i0], 0.0f);
  const float a1 = fmaxf(frow[i1], 0.0f);
  up = __fadd_rn(__fmul_rn(a0, __fsub_rn(1.0f, w)), __fmul_rn(a1, w));
  d = __fmul_rn(up, R48000);
}

// Kernel A: one block per row. Thread serially sums its 960 samples' d's in
// f64, block-wide f64 scan, store frac(prefix) at every 64-sample strip.
__global__ __launch_bounds__(1024) void span_scan(
    const float* __restrict__ f0, float* __restrict__ stripFrac, int L, int T) {
  const int row = blockIdx.x;
  const int tid = threadIdx.x;
  const float* frow = f0 + row * L;

  double inter[NSTORE];  // prefix-before-strip-k (statically indexed)
  double local = 0.0;
  const int t0 = tid * SPAN;
  if (tid < ATHREADS) {
#pragma unroll
    for (int k = 0; k < NSTORE; ++k) {
      inter[k] = local;
      const int tb = t0 + k * STRIP;
      for (int j = 0; j < STRIP; ++j) {
        float up, d;
        sample_udA(frow, L, tb + j, up, d);
        local += (double)d;
      }
    }
  }

  const int lane = tid & 63, wid = tid >> 6;
  __shared__ double wsum[16];
  double run = local;
#pragma unroll
  for (int s = 1; s < 64; s <<= 1) {
    double o = __shfl_up(run, s, 64);
    if (lane >= s) run += o;
  }
  if (lane == 63) wsum[wid] = run;
  __syncthreads();
  if (wid == 0) {
    double wv = (lane < 16) ? wsum[lane] : 0.0;
    double wr = wv;
#pragma unroll
    for (int s = 1; s < 16; s <<= 1) {
      double o = __shfl_up(wr, s, 64);
      if (lane >= s) wr += o;
    }
    if (lane < 16) wsum[lane] = wr - wv;  // exclusive wave offsets
  }
  __syncthreads();
  const double base = wsum[wid] + (run - local);  // exclusive thread prefix

  if (tid < ATHREADS) {
    float* sf = stripFrac + (size_t)row * (ATHREADS * NSTORE);
#pragma unroll
    for (int k = 0; k < NSTORE; ++k) {
      double p = base + inter[k];
      sf[tid * NSTORE + k] = (float)(p - floor(p));
    }
  }
}

// Kernel B: one wave per 64-sample strip. Per-lane (up,d), f64 inclusive
// wave scan, phase = strip frac + scan; voiced flag from candidate-A f32 up.
__global__ __launch_bounds__(256) void emit_k(
    const float* __restrict__ f0, const float* __restrict__ noise,
    const float* __restrict__ stripFrac, float* __restrict__ out,
    int L, int T) {
  const int gw = (int)((blockIdx.x * (unsigned)blockDim.x + threadIdx.x) >> 6);
  const int lane = threadIdx.x & 63;
  const int nStrips = T / STRIP;  // 15000
  const int row = gw / nStrips;
  const int strip = gw - row * nStrips;
  if (row >= NROWS) return;

  const float* frow = f0 + row * L;
  const int t = strip * STRIP + lane;

  float up, dA;
  sample_udA(frow, L, t, up, dA);
  const double d = (double)dA;

  double run = d;  // inclusive scan over the wave (f64)
#pragma unroll
  for (int s = 1; s < 64; s <<= 1) {
    double o = __shfl_up(run, s, 64);
    if (lane >= s) run += o;
  }

  const double ph = (double)stripFrac[(size_t)row * nStrips + strip] + run;
  const float fr = (float)(ph - floor(ph));   // revolutions in [0,1)
  const float s = __builtin_amdgcn_sinf(fr);  // sin(2*pi*fr), HW v_sin_f32

  const float n = noise[(size_t)row * T + t];
  const float v = __fadd_rn(s, __fmul_rn(0.03f, n));
  const float u = __fmul_rn(0.3f, n);
  out[(size_t)row * T + t] = (up > 20.0f) ? v : u;
}

extern "C" void kernel_launch(void* const* d_in, const int* in_sizes, int n_in,
                              void* d_out, int out_size, void* d_ws, size_t ws_size,
                              hipStream_t stream) {
  const float* f0    = (const float*)d_in[0];
  const float* noise = (const float*)d_in[1];
  float* out = (float*)d_out;
  float* stripFrac = (float*)d_ws;  // 32 * 15000 f32 = 1.92 MB

  const int L = in_sizes[0] / NROWS;  // 2000
  const int T = in_sizes[1] / NROWS;  // 960000

  span_scan<<<NROWS, 1024, 0, stream>>>(f0, stripFrac, L, T);

  const int nStrips = T / STRIP;                 // 15000
  const long long totalThreads = (long long)NROWS * nStrips * 64;
  const int blocks = (int)(totalThreads / 256);  // 120000 exact
  emit_k<<<blocks, 256, 0, stream>>>(f0, noise, stripFrac, out, L, T);
}

// Round 9
// 79.746 us; speedup vs baseline: 3.8469x; 3.8469x over previous
//
#include <hip/hip_runtime.h>

#define NROWS 32
#define SSTRIP 256    // samples per strip (4 per lane, one wave per strip)
#define NSTRIPS 3750  // strips per row = 960000 / 256

// XLA-CPU f32 mirror: division-by-constant rewritten to multiply by the f32
// reciprocal (validated round 8). No FMA contraction.
__device__ __forceinline__ void sample_udA(const float* __restrict__ frow,
                                           int L, int t, float& up, float& d) {
  const float R480 = 1.0f / 480.0f;      // RN(1/480)
  const float R48000 = 1.0f / 48000.0f;  // RN(1/48000)
  float x = __fsub_rn(__fmul_rn(__fadd_rn((float)t, 0.5f), R480), 0.5f);
  x = fminf(fmaxf(x, 0.0f), (float)(L - 1));
  const int i0 = (int)x;                    // x >= 0: trunc == floor
  const float w = __fsub_rn(x, (float)i0);  // exact
  const int i1 = min(i0 + 1, L - 1);
  const float a0 = fmaxf(frow[i0], 0.0f);
  const float a1 = fmaxf(frow[i1], 0.0f);
  up = __fadd_rn(__fmul_rn(a0, __fsub_rn(1.0f, w)), __fmul_rn(a1, w));
  d = __fmul_rn(up, R48000);
}

// Kernel A: one wave per 256-sample strip -> f64 strip total (full-chip
// parallel; replaces the 32-block latency-bound span_scan).
__global__ __launch_bounds__(256) void strip_sum(
    const float* __restrict__ f0, double* __restrict__ stripSum, int L, int T) {
  const int gw = (int)((blockIdx.x * 256u + threadIdx.x) >> 6);
  const int lane = threadIdx.x & 63;
  const int row = gw / NSTRIPS;
  const int strip = gw - row * NSTRIPS;
  if (row >= NROWS) return;
  const float* frow = f0 + row * L;
  const int tb = strip * SSTRIP + lane * 4;

  double s = 0.0;
#pragma unroll
  for (int k = 0; k < 4; ++k) {
    float up, d;
    sample_udA(frow, L, tb + k, up, d);
    s += (double)d;
  }
#pragma unroll
  for (int sh = 1; sh < 64; sh <<= 1) {
    double o = __shfl_up(s, sh, 64);
    if (lane >= sh) s += o;
  }
  if (lane == 63) stripSum[(size_t)row * NSTRIPS + strip] = s;
}

// Kernel B: per-row f64 scan of the 3750 strip totals -> f32 frac bases.
__global__ __launch_bounds__(1024) void strip_scan(
    const double* __restrict__ stripSum, float* __restrict__ stripFrac) {
  const int row = blockIdx.x;
  const int tid = threadIdx.x;
  const int s0 = tid * 4;

  double pre[4];  // prefix-before-strip within this thread (static idx)
  double local = 0.0;
#pragma unroll
  for (int k = 0; k < 4; ++k) {
    const int s = s0 + k;
    pre[k] = local;
    if (s < NSTRIPS) local += stripSum[(size_t)row * NSTRIPS + s];
  }

  const int lane = tid & 63, wid = tid >> 6;
  __shared__ double wsum[16];
  double run = local;
#pragma unroll
  for (int sh = 1; sh < 64; sh <<= 1) {
    double o = __shfl_up(run, sh, 64);
    if (lane >= sh) run += o;
  }
  if (lane == 63) wsum[wid] = run;
  __syncthreads();
  if (wid == 0) {
    double wv = (lane < 16) ? wsum[lane] : 0.0;
    double wr = wv;
#pragma unroll
    for (int sh = 1; sh < 16; sh <<= 1) {
      double o = __shfl_up(wr, sh, 64);
      if (lane >= sh) wr += o;
    }
    if (lane < 16) wsum[lane] = wr - wv;  // exclusive wave offsets
  }
  __syncthreads();
  const double base = wsum[wid] + (run - local);  // exclusive thread prefix

#pragma unroll
  for (int k = 0; k < 4; ++k) {
    const int s = s0 + k;
    if (s < NSTRIPS) {
      const double p = base + pre[k];
      stripFrac[(size_t)row * NSTRIPS + s] = (float)(p - floor(p));
    }
  }
}

// Kernel C: one wave per 256-sample strip; 4 contiguous samples per lane ->
// float4 noise/out; one f64 wave scan per strip, per-lane running phase.
__global__ __launch_bounds__(256) void emit_k(
    const float* __restrict__ f0, const float* __restrict__ noise,
    const float* __restrict__ stripFrac, float* __restrict__ out,
    int L, int T) {
  const int gw = (int)((blockIdx.x * 256u + threadIdx.x) >> 6);
  const int lane = threadIdx.x & 63;
  const int row = gw / NSTRIPS;
  const int strip = gw - row * NSTRIPS;
  if (row >= NROWS) return;
  const float* frow = f0 + row * L;
  const int tb = strip * SSTRIP + lane * 4;

  float up[4];
  double d[4];
  double s = 0.0;
#pragma unroll
  for (int k = 0; k < 4; ++k) {
    float u, dd;
    sample_udA(frow, L, tb + k, u, dd);
    up[k] = u;
    d[k] = (double)dd;
    s += d[k];
  }

  double run = s;  // inclusive wave scan of per-lane sums
#pragma unroll
  for (int sh = 1; sh < 64; sh <<= 1) {
    double o = __shfl_up(run, sh, 64);
    if (lane >= sh) run += o;
  }
  double ph = (double)stripFrac[(size_t)row * NSTRIPS + strip] + (run - s);

  const float4 nz =
      *reinterpret_cast<const float4*>(noise + (size_t)row * T + tb);
  const float nv[4] = {nz.x, nz.y, nz.z, nz.w};
  float ov[4];
#pragma unroll
  for (int k = 0; k < 4; ++k) {
    ph += d[k];
    const float fr = (float)(ph - floor(ph));     // revolutions in [0,1)
    const float sn = __builtin_amdgcn_sinf(fr);   // sin(2*pi*fr), v_sin_f32
    const float v = __fadd_rn(sn, __fmul_rn(0.03f, nv[k]));
    const float u = __fmul_rn(0.3f, nv[k]);
    ov[k] = (up[k] > 20.0f) ? v : u;
  }
  *reinterpret_cast<float4*>(out + (size_t)row * T + tb) =
      make_float4(ov[0], ov[1], ov[2], ov[3]);
}

extern "C" void kernel_launch(void* const* d_in, const int* in_sizes, int n_in,
                              void* d_out, int out_size, void* d_ws, size_t ws_size,
                              hipStream_t stream) {
  const float* f0    = (const float*)d_in[0];
  const float* noise = (const float*)d_in[1];
  float* out = (float*)d_out;
  double* stripSum = (double*)d_ws;                        // 120000 f64 = 960 KB
  float* stripFrac = (float*)(stripSum + NROWS * NSTRIPS); // 120000 f32 = 480 KB

  const int L = in_sizes[0] / NROWS;  // 2000
  const int T = in_sizes[1] / NROWS;  // 960000

  const int nWaves = NROWS * NSTRIPS;        // 120000
  const int blocks = nWaves / 4;             // 30000 blocks of 256

  strip_sum<<<blocks, 256, 0, stream>>>(f0, stripSum, L, T);
  strip_scan<<<NROWS, 1024, 0, stream>>>(stripSum, stripFrac);
  emit_k<<<blocks, 256, 0, stream>>>(f0, noise, stripFrac, out, L, T);
}

// Round 10
// 67.972 us; speedup vs baseline: 4.5133x; 1.1732x over previous
//
#include <hip/hip_runtime.h>

#define NROWS 32
#define SSTRIP 512    // samples per strip (8 per lane, one wave per strip)
#define NSTRIPS 1875  // strips per row = 960000 / 512
#define SPL 8         // samples per lane

// XLA-CPU f32 mirror: division-by-constant rewritten to multiply by the f32
// reciprocal (validated round 8). No FMA contraction.
__device__ __forceinline__ void sample_udA(const float* __restrict__ frow,
                                           int L, int t, float& up, float& d) {
  const float R480 = 1.0f / 480.0f;      // RN(1/480)
  const float R48000 = 1.0f / 48000.0f;  // RN(1/48000)
  float x = __fsub_rn(__fmul_rn(__fadd_rn((float)t, 0.5f), R480), 0.5f);
  x = fminf(fmaxf(x, 0.0f), (float)(L - 1));
  const int i0 = (int)x;                    // x >= 0: trunc == floor
  const float w = __fsub_rn(x, (float)i0);  // exact
  const int i1 = min(i0 + 1, L - 1);
  const float a0 = fmaxf(frow[i0], 0.0f);
  const float a1 = fmaxf(frow[i1], 0.0f);
  up = __fadd_rn(__fmul_rn(a0, __fsub_rn(1.0f, w)), __fmul_rn(a1, w));
  d = __fmul_rn(up, R48000);
}

// Kernel A: one wave per 512-sample strip -> f64 strip total via butterfly.
__global__ __launch_bounds__(256) void strip_sum(
    const float* __restrict__ f0, double* __restrict__ stripSum, int L, int T) {
  const int gw = (int)((blockIdx.x * 256u + threadIdx.x) >> 6);
  const int lane = threadIdx.x & 63;
  const int row = gw / NSTRIPS;
  const int strip = gw - row * NSTRIPS;
  if (row >= NROWS) return;
  const float* frow = f0 + row * L;
  const int tb = strip * SSTRIP + lane * SPL;

  double s = 0.0;
#pragma unroll
  for (int k = 0; k < SPL; ++k) {
    float up, d;
    sample_udA(frow, L, tb + k, up, d);
    s += (double)d;
  }
#pragma unroll
  for (int sh = 32; sh >= 1; sh >>= 1) s += __shfl_xor(s, sh, 64);
  if (lane == 0) stripSum[(size_t)row * NSTRIPS + strip] = s;
}

// Kernel B: per-row f64 scan of the 1875 strip totals -> f32 frac bases.
__global__ __launch_bounds__(1024) void strip_scan(
    const double* __restrict__ stripSum, float* __restrict__ stripFrac) {
  const int row = blockIdx.x;
  const int tid = threadIdx.x;
  const int s0 = tid * 2;

  double pre[2];  // prefix-before-strip within this thread (static idx)
  double local = 0.0;
#pragma unroll
  for (int k = 0; k < 2; ++k) {
    const int s = s0 + k;
    pre[k] = local;
    if (s < NSTRIPS) local += stripSum[(size_t)row * NSTRIPS + s];
  }

  const int lane = tid & 63, wid = tid >> 6;
  __shared__ double wsum[16];
  double run = local;
#pragma unroll
  for (int sh = 1; sh < 64; sh <<= 1) {
    double o = __shfl_up(run, sh, 64);
    if (lane >= sh) run += o;
  }
  if (lane == 63) wsum[wid] = run;
  __syncthreads();
  if (wid == 0) {
    double wv = (lane < 16) ? wsum[lane] : 0.0;
    double wr = wv;
#pragma unroll
    for (int sh = 1; sh < 16; sh <<= 1) {
      double o = __shfl_up(wr, sh, 64);
      if (lane >= sh) wr += o;
    }
    if (lane < 16) wsum[lane] = wr - wv;  // exclusive wave offsets
  }
  __syncthreads();
  const double base = wsum[wid] + (run - local);  // exclusive thread prefix

#pragma unroll
  for (int k = 0; k < 2; ++k) {
    const int s = s0 + k;
    if (s < NSTRIPS) {
      const double p = base + pre[k];
      stripFrac[(size_t)row * NSTRIPS + s] = (float)(p - floor(p));
    }
  }
}

// Kernel C: one wave per 512-sample strip; 8 contiguous samples per lane ->
// 2x float4 noise/out; one f64 wave scan per strip, per-lane running phase.
__global__ __launch_bounds__(256) void emit_k(
    const float* __restrict__ f0, const float* __restrict__ noise,
    const float* __restrict__ stripFrac, float* __restrict__ out,
    int L, int T) {
  const int gw = (int)((blockIdx.x * 256u + threadIdx.x) >> 6);
  const int lane = threadIdx.x & 63;
  const int row = gw / NSTRIPS;
  const int strip = gw - row * NSTRIPS;
  if (row >= NROWS) return;
  const float* frow = f0 + row * L;
  const int tb = strip * SSTRIP + lane * SPL;

  float up[SPL];
  double d[SPL];
  double s = 0.0;
#pragma unroll
  for (int k = 0; k < SPL; ++k) {
    float u, dd;
    sample_udA(frow, L, tb + k, u, dd);
    up[k] = u;
    d[k] = (double)dd;
    s += d[k];
  }

  double run = s;  // inclusive wave scan of per-lane sums
#pragma unroll
  for (int sh = 1; sh < 64; sh <<= 1) {
    double o = __shfl_up(run, sh, 64);
    if (lane >= sh) run += o;
  }
  double ph = (double)stripFrac[(size_t)row * NSTRIPS + strip] + (run - s);

  const float* np_ = noise + (size_t)row * T + tb;
  const float4 nz0 = *reinterpret_cast<const float4*>(np_);
  const float4 nz1 = *reinterpret_cast<const float4*>(np_ + 4);
  const float nv[SPL] = {nz0.x, nz0.y, nz0.z, nz0.w,
                         nz1.x, nz1.y, nz1.z, nz1.w};
  float ov[SPL];
#pragma unroll
  for (int k = 0; k < SPL; ++k) {
    ph += d[k];
    const float fr = (float)(ph - floor(ph));     // revolutions in [0,1)
    const float sn = __builtin_amdgcn_sinf(fr);   // sin(2*pi*fr), v_sin_f32
    const float v = __fadd_rn(sn, __fmul_rn(0.03f, nv[k]));
    const float u = __fmul_rn(0.3f, nv[k]);
    ov[k] = (up[k] > 20.0f) ? v : u;
  }
  float* op_ = out + (size_t)row * T + tb;
  *reinterpret_cast<float4*>(op_) = make_float4(ov[0], ov[1], ov[2], ov[3]);
  *reinterpret_cast<float4*>(op_ + 4) = make_float4(ov[4], ov[5], ov[6], ov[7]);
}

extern "C" void kernel_launch(void* const* d_in, const int* in_sizes, int n_in,
                              void* d_out, int out_size, void* d_ws, size_t ws_size,
                              hipStream_t stream) {
  const float* f0    = (const float*)d_in[0];
  const float* noise = (const float*)d_in[1];
  float* out = (float*)d_out;
  double* stripSum = (double*)d_ws;                        // 60000 f64 = 480 KB
  float* stripFrac = (float*)(stripSum + NROWS * NSTRIPS); // 60000 f32 = 240 KB

  const int L = in_sizes[0] / NROWS;  // 2000
  const int T = in_sizes[1] / NROWS;  // 960000

  const int nWaves = NROWS * NSTRIPS;  // 60000
  const int blocks = nWaves / 4;       // 15000 blocks of 256

  strip_sum<<<blocks, 256, 0, stream>>>(f0, stripSum, L, T);
  strip_scan<<<NROWS, 1024, 0, stream>>>(stripSum, stripFrac);
  emit_k<<<blocks, 256, 0, stream>>>(f0, noise, stripFrac, out, L, T);
}

// Round 11
// 47.302 us; speedup vs baseline: 6.4855x; 1.4370x over previous
//
#include <hip/hip_runtime.h>

#define NROWS 32
#define SSTRIP 512    // samples per strip (8 per lane, one wave per strip)
#define NSTRIPS 1875  // strips per row = 960000 / 512
#define SPL 8         // samples per lane
#define FRAME 480
#define LFRAMES 2000

// Exact f64 value of the f32 reciprocal the ref multiplies by (validated r8).
#define R48000D ((double)(1.0f / 48000.0f))

// XLA-CPU f32 mirror: division-by-constant rewritten to multiply by the f32
// reciprocal (validated round 8). No FMA contraction.
__device__ __forceinline__ void sample_udA(const float* __restrict__ frow,
                                           int L, int t, float& up, float& d) {
  const float R480 = 1.0f / 480.0f;      // RN(1/480)
  const float R48000 = 1.0f / 48000.0f;  // RN(1/48000)
  float x = __fsub_rn(__fmul_rn(__fadd_rn((float)t, 0.5f), R480), 0.5f);
  x = fminf(fmaxf(x, 0.0f), (float)(L - 1));
  const int i0 = (int)x;                    // x >= 0: trunc == floor
  const float w = __fsub_rn(x, (float)i0);  // exact
  const int i1 = min(i0 + 1, L - 1);
  const float a0 = fmaxf(frow[i0], 0.0f);
  const float a1 = fmaxf(frow[i1], 0.0f);
  up = __fadd_rn(__fmul_rn(a0, __fsub_rn(1.0f, w)), __fmul_rn(a1, w));
  d = __fmul_rn(up, R48000);
}

// Per-frame sum of up (in Hz*samples, exact a-values), closed form.
// Algebra validated empirically: r1/r6 and r4/r5 bit-identical absmax pairs.
__device__ __forceinline__ double frame_sum_u(const float* __restrict__ frow,
                                              int l, int L) {
  const double a  = (double)fmaxf(frow[l], 0.0f);
  const double ap = (l > 0) ? (double)fmaxf(frow[l - 1], 0.0f) : 0.0;
  const double an = (l < L - 1) ? (double)fmaxf(frow[l + 1], 0.0f) : 0.0;
  double wp = 60.0, wc = 360.0, wn = 60.0;
  if (l == 0)     { wp = 0.0; wc = 420.0; }
  if (l == L - 1) { wn = 0.0; wc = 420.0; }
  return wp * ap + wc * a + wn * an;
}

// Kernel A: one block per row. Frame sums -> block f64 scan -> framePre in
// LDS -> stripFrac via closed-form partial-frame prefixes.
__global__ __launch_bounds__(1024) void frame_scan(
    const float* __restrict__ f0, float* __restrict__ stripFrac, int L) {
  const int row = blockIdx.x;
  const int tid = threadIdx.x;
  const float* frow = f0 + row * L;

  __shared__ double framePre[LFRAMES];  // exclusive prefix, up-units
  __shared__ double wsum[16];

  // 2 frames per thread (threads 0..999)
  double fs0 = 0.0, fs1 = 0.0;
  const int l0 = tid * 2;
  if (l0 < LFRAMES) {
    fs0 = frame_sum_u(frow, l0, L);
    fs1 = frame_sum_u(frow, l0 + 1, L);
  }
  double local = fs0 + fs1;

  const int lane = tid & 63, wid = tid >> 6;
  double run = local;
#pragma unroll
  for (int sh = 1; sh < 64; sh <<= 1) {
    double o = __shfl_up(run, sh, 64);
    if (lane >= sh) run += o;
  }
  if (lane == 63) wsum[wid] = run;
  __syncthreads();
  if (wid == 0) {
    double wv = (lane < 16) ? wsum[lane] : 0.0;
    double wr = wv;
#pragma unroll
    for (int sh = 1; sh < 16; sh <<= 1) {
      double o = __shfl_up(wr, sh, 64);
      if (lane >= sh) wr += o;
    }
    if (lane < 16) wsum[lane] = wr - wv;  // exclusive wave offsets
  }
  __syncthreads();
  const double base = wsum[wid] + (run - local);  // exclusive thread prefix
  if (l0 < LFRAMES) {
    framePre[l0] = base;
    framePre[l0 + 1] = base + fs0;
  }
  __syncthreads();

  // stripFrac: phase before sample 512*s, closed-form partial within frame.
  for (int s = tid; s < NSTRIPS; s += 1024) {
    const int t0 = s * SSTRIP;
    const int l = t0 / FRAME;
    const int c = t0 - l * FRAME;  // samples of frame l before strip start
    const double a = (double)fmaxf(frow[l], 0.0f);
    double partial;
    if (c == 0) {
      partial = 0.0;
    } else if (c <= 240) {
      if (l == 0) {
        partial = (double)c * a;
      } else {
        const double ap = (double)fmaxf(frow[l - 1], 0.0f);
        partial = (double)c * ap +
                  (a - ap) * ((double)c * (c + 480)) * (1.0 / 960.0);
      }
    } else {
      const double ap = (l > 0) ? (double)fmaxf(frow[l - 1], 0.0f) : a;
      const double H1 = (l == 0) ? 240.0 * a : 60.0 * ap + 180.0 * a;
      const int m0 = c - 240;
      if (l == L - 1) {
        partial = H1 + (double)m0 * a;
      } else {
        const double an = (double)fmaxf(frow[l + 1], 0.0f);
        partial = H1 + (double)m0 * a +
                  (an - a) * ((double)m0 * m0) * (1.0 / 960.0);
      }
    }
    const double p = (framePre[l] + partial) * R48000D;
    stripFrac[(size_t)row * NSTRIPS + s] = (float)(p - floor(p));
  }
}

// Kernel B: one wave per 512-sample strip; 8 contiguous samples per lane ->
// 2x float4 noise/out; one f64 wave scan per strip, per-lane running phase.
__global__ __launch_bounds__(256) void emit_k(
    const float* __restrict__ f0, const float* __restrict__ noise,
    const float* __restrict__ stripFrac, float* __restrict__ out,
    int L, int T) {
  const int gw = (int)((blockIdx.x * 256u + threadIdx.x) >> 6);
  const int lane = threadIdx.x & 63;
  const int row = gw / NSTRIPS;
  const int strip = gw - row * NSTRIPS;
  if (row >= NROWS) return;
  const float* frow = f0 + row * L;
  const int tb = strip * SSTRIP + lane * SPL;

  float up[SPL];
  float dd[SPL];
  double s = 0.0;
#pragma unroll
  for (int k = 0; k < SPL; ++k) {
    sample_udA(frow, L, tb + k, up[k], dd[k]);
    s += (double)dd[k];
  }

  double run = s;  // inclusive wave scan of per-lane sums
#pragma unroll
  for (int sh = 1; sh < 64; sh <<= 1) {
    double o = __shfl_up(run, sh, 64);
    if (lane >= sh) run += o;
  }
  double ph = (double)stripFrac[(size_t)row * NSTRIPS + strip] + (run - s);

  const float* np_ = noise + (size_t)row * T + tb;
  const float4 nz0 = *reinterpret_cast<const float4*>(np_);
  const float4 nz1 = *reinterpret_cast<const float4*>(np_ + 4);
  const float nv[SPL] = {nz0.x, nz0.y, nz0.z, nz0.w,
                         nz1.x, nz1.y, nz1.z, nz1.w};
  float ov[SPL];
#pragma unroll
  for (int k = 0; k < SPL; ++k) {
    ph += (double)dd[k];
    const float fr = (float)(ph - floor(ph));     // revolutions in [0,1)
    const float sn = __builtin_amdgcn_sinf(fr);   // sin(2*pi*fr), v_sin_f32
    const float v = __fadd_rn(sn, __fmul_rn(0.03f, nv[k]));
    const float u = __fmul_rn(0.3f, nv[k]);
    ov[k] = (up[k] > 20.0f) ? v : u;
  }
  float* op_ = out + (size_t)row * T + tb;
  *reinterpret_cast<float4*>(op_) = make_float4(ov[0], ov[1], ov[2], ov[3]);
  *reinterpret_cast<float4*>(op_ + 4) = make_float4(ov[4], ov[5], ov[6], ov[7]);
}

extern "C" void kernel_launch(void* const* d_in, const int* in_sizes, int n_in,
                              void* d_out, int out_size, void* d_ws, size_t ws_size,
                              hipStream_t stream) {
  const float* f0    = (const float*)d_in[0];
  const float* noise = (const float*)d_in[1];
  float* out = (float*)d_out;
  float* stripFrac = (float*)d_ws;  // 60000 f32 = 240 KB

  const int L = in_sizes[0] / NROWS;  // 2000
  const int T = in_sizes[1] / NROWS;  // 960000

  frame_scan<<<NROWS, 1024, 0, stream>>>(f0, stripFrac, L);

  const int nWaves = NROWS * NSTRIPS;  // 60000
  const int blocks = nWaves / 4;       // 15000 blocks of 256
  emit_k<<<blocks, 256, 0, stream>>>(f0, noise, stripFrac, out, L, T);
}